// Round 2
// baseline (1142.664 us; speedup 1.0000x reference)
//
#include <hip/hip_runtime.h>
#include <hip/hip_bf16.h>

// ---------------- LayerNorm: one block (256 thr) per 512-elem row ----------
__global__ __launch_bounds__(256) void ln_kernel(const float* __restrict__ in,
    const float* __restrict__ w, const float* __restrict__ bb,
    float* __restrict__ out)
{
  const int row = blockIdx.x;
  const int tid = threadIdx.x;
  const long base = (long)row * 512;
  float v0 = in[base + tid];
  float v1 = in[base + 256 + tid];
  float s = v0 + v1, ss = v0*v0 + v1*v1;
  #pragma unroll
  for (int o = 32; o > 0; o >>= 1){ s += __shfl_down(s, o); ss += __shfl_down(ss, o); }
  __shared__ float rA[4], rB[4];
  const int wid = tid >> 6, lid = tid & 63;
  if (lid == 0){ rA[wid] = s; rB[wid] = ss; }
  __syncthreads();
  s  = rA[0] + rA[1] + rA[2] + rA[3];
  ss = rB[0] + rB[1] + rB[2] + rB[3];
  float mu  = s * (1.f/512.f);
  float var = ss * (1.f/512.f) - mu*mu;
  float r   = rsqrtf(var + 1e-5f);
  out[base + tid]       = (v0 - mu) * r * w[tid]       + bb[tid];
  out[base + 256 + tid] = (v1 - mu) * r * w[256 + tid] + bb[256 + tid];
}

// ---------------- Generic fp32 tiled GEMM (NN), 64x64 tile, BK=16 ----------
// EPI: 0 = C=acc ; 1 = +bias ; 2 = +bias+res ; 3 = gelu(acc+bias)
template<int EPI, int BDIV>
__global__ __launch_bounds__(256) void gemm_nn(
    const float* __restrict__ A, const float* __restrict__ Bm, float* __restrict__ C,
    int M, int N, int Kd, int lda, int ldb, int ldc,
    long sA, long sA2, long sB, long sB2, long sC, long sC2,
    const float* __restrict__ bias, const float* __restrict__ res)
{
  const int bz = blockIdx.z;
  A  += (long)(bz / BDIV) * sA + (long)(bz % BDIV) * sA2;
  Bm += (long)(bz / BDIV) * sB + (long)(bz % BDIV) * sB2;
  C  += (long)(bz / BDIV) * sC + (long)(bz % BDIV) * sC2;
  __shared__ float As[16][68];
  __shared__ float Bs[16][64];
  const int tid = threadIdx.x;
  const int tx = tid & 15, ty = tid >> 4;
  const int m0 = blockIdx.y * 64, n0 = blockIdx.x * 64;
  float acc[4][4] = {};
  for (int k0 = 0; k0 < Kd; k0 += 16){
    #pragma unroll
    for (int i = 0; i < 4; i++){
      int r = (tid >> 4) + i*16, c = tid & 15;
      As[c][r] = A[(long)(m0 + r) * lda + (k0 + c)];
    }
    #pragma unroll
    for (int i = 0; i < 4; i++){
      int r = (tid >> 6) + i*4, c = tid & 63;
      Bs[r][c] = Bm[(long)(k0 + r) * ldb + (n0 + c)];
    }
    __syncthreads();
    #pragma unroll
    for (int kk = 0; kk < 16; kk++){
      float a[4], b[4];
      #pragma unroll
      for (int i = 0; i < 4; i++) a[i] = As[kk][ty*4 + i];
      #pragma unroll
      for (int j = 0; j < 4; j++) b[j] = Bs[kk][tx*4 + j];
      #pragma unroll
      for (int i = 0; i < 4; i++)
        #pragma unroll
        for (int j = 0; j < 4; j++) acc[i][j] += a[i] * b[j];
    }
    __syncthreads();
  }
  #pragma unroll
  for (int i = 0; i < 4; i++){
    int m = m0 + ty*4 + i;
    #pragma unroll
    for (int j = 0; j < 4; j++){
      int n = n0 + tx*4 + j;
      float v = acc[i][j];
      if (EPI >= 1) v += bias[n];
      if (EPI == 2) v += res[(long)m * ldc + n];
      if (EPI == 3) v = 0.5f * v * (1.f + erff(v * 0.70710678118f));
      C[(long)m * ldc + n] = v;
    }
  }
}

// ---------------- scores += 0.125 * Q @ K^T  (per b,h batch) ---------------
__global__ __launch_bounds__(256) void gemm_qk(const float* __restrict__ qkv,
                                               float* __restrict__ scores)
{
  const int bz = blockIdx.z;           // b*8+h
  const int b = bz >> 3, h = bz & 7;
  const float* A  = qkv + (long)b * 786432 + h * 64;        // Q rows, stride 1536
  const float* Bm = qkv + (long)b * 786432 + 512 + h * 64;  // K rows, stride 1536
  float* C = scores + (long)bz * 262144;
  __shared__ float As[16][68], Bs[16][68];
  const int tid = threadIdx.x;
  const int tx = tid & 15, ty = tid >> 4;
  const int m0 = blockIdx.y * 64, n0 = blockIdx.x * 64;
  float acc[4][4] = {};
  for (int k0 = 0; k0 < 64; k0 += 16){
    #pragma unroll
    for (int i = 0; i < 4; i++){
      int r = (tid >> 4) + i*16, c = tid & 15;
      As[c][r] = A[(long)(m0 + r) * 1536 + k0 + c];
      Bs[c][r] = Bm[(long)(n0 + r) * 1536 + k0 + c];
    }
    __syncthreads();
    #pragma unroll
    for (int kk = 0; kk < 16; kk++){
      float a[4], bv[4];
      #pragma unroll
      for (int i = 0; i < 4; i++) a[i]  = As[kk][ty*4 + i];
      #pragma unroll
      for (int j = 0; j < 4; j++) bv[j] = Bs[kk][tx*4 + j];
      #pragma unroll
      for (int i = 0; i < 4; i++)
        #pragma unroll
        for (int j = 0; j < 4; j++) acc[i][j] += a[i] * bv[j];
    }
    __syncthreads();
  }
  #pragma unroll
  for (int i = 0; i < 4; i++){
    int m = m0 + ty*4 + i;
    #pragma unroll
    for (int j = 0; j < 4; j++){
      int n = n0 + tx*4 + j;
      C[(long)m * 512 + n] += 0.125f * acc[i][j];
    }
  }
}

// ---------------- softmax over rows of 512 ---------------------------------
__global__ __launch_bounds__(256) void softmax_kernel(float* __restrict__ sc)
{
  const long base = (long)blockIdx.x * 512;
  const int tid = threadIdx.x;
  float a = sc[base + tid], b = sc[base + 256 + tid];
  float m = fmaxf(a, b);
  #pragma unroll
  for (int o = 32; o > 0; o >>= 1) m = fmaxf(m, __shfl_xor(m, o));
  __shared__ float rA[4], rB[4];
  const int wid = tid >> 6, lid = tid & 63;
  if (lid == 0) rA[wid] = m;
  __syncthreads();
  m = fmaxf(fmaxf(rA[0], rA[1]), fmaxf(rA[2], rA[3]));
  float ea = __expf(a - m), eb = __expf(b - m);
  float s = ea + eb;
  #pragma unroll
  for (int o = 32; o > 0; o >>= 1) s += __shfl_xor(s, o);
  if (lid == 0) rB[wid] = s;
  __syncthreads();
  s = rB[0] + rB[1] + rB[2] + rB[3];
  float inv = 1.f / s;
  sc[base + tid]       = ea * inv;
  sc[base + 256 + tid] = eb * inv;
}

// ---------------- edge bias: scores[b,h,q,k] = pairwise[b,q,k,:]·edge_w[:,h] + edge_b[h]
// 16 lanes per (q,k) pair; each lane loads 8 floats (32B); staged
// head-splitting butterfly reduce over the 16 lanes.
__global__ __launch_bounds__(256) void edge_bias_kernel(
    const float* __restrict__ pw,
    const float* __restrict__ edge_w,
    const float* __restrict__ edge_b,
    float* __restrict__ scores)
{
  const int tid  = threadIdx.x;
  const int lane = tid & 63;
  const int wid  = tid >> 6;
  const int sub  = lane & 15;
  const int quad = lane >> 4;
  float ew[8][8];
  #pragma unroll
  for (int j = 0; j < 8; j++)
    #pragma unroll
    for (int h = 0; h < 8; h++)
      ew[j][h] = edge_w[(sub*8 + j)*8 + h];
  const int b3 = (sub >> 3) & 1, b2_ = (sub >> 2) & 1, b1 = (sub >> 1) & 1;
  const int myh = b3*4 + b2_*2 + b1;
  const float ebh = edge_b[myh];
  const long total = 1048576;  // 4*512*512 pairs
  for (long base = (long)blockIdx.x * 16; base < total; base += (long)gridDim.x * 16){
    long pair = base + wid*4 + quad;
    const float* src = pw + pair * 128 + sub * 8;
    float4 r0 = *reinterpret_cast<const float4*>(src);
    float4 r1 = *reinterpret_cast<const float4*>(src + 4);
    float x[8] = {r0.x, r0.y, r0.z, r0.w, r1.x, r1.y, r1.z, r1.w};
    float acc[8] = {0,0,0,0,0,0,0,0};
    #pragma unroll
    for (int j = 0; j < 8; j++)
      #pragma unroll
      for (int h = 0; h < 8; h++)
        acc[h] += x[j] * ew[j][h];
    // reduce across 16 lanes, splitting heads each stage
    float t[4];
    #pragma unroll
    for (int i = 0; i < 4; i++){
      float send = b3 ? acc[i] : acc[i+4];
      float keep = b3 ? acc[i+4] : acc[i];
      t[i] = keep + __shfl_xor(send, 8);
    }
    float u[2];
    #pragma unroll
    for (int i = 0; i < 2; i++){
      float send = b2_ ? t[i] : t[i+2];
      float keep = b2_ ? t[i+2] : t[i];
      u[i] = keep + __shfl_xor(send, 4);
    }
    float send = b1 ? u[0] : u[1];
    float keep = b1 ? u[1] : u[0];
    float val = keep + __shfl_xor(send, 2);
    val += __shfl_xor(val, 1);
    if ((sub & 1) == 0){
      long b  = pair >> 18;        // 512*512 = 2^18
      long qk = pair & 262143;
      scores[(b*8 + myh) * 262144 + qk] = val + ebh;
    }
  }
}

// ---------------------------------------------------------------------------
extern "C" void kernel_launch(void* const* d_in, const int* in_sizes, int n_in,
                              void* d_out, int out_size, void* d_ws, size_t ws_size,
                              hipStream_t stream)
{
  const float* slots    = (const float*)d_in[0];
  const float* pairwise = (const float*)d_in[1];
  const float* ln1_w    = (const float*)d_in[2];
  const float* ln1_b    = (const float*)d_in[3];
  const float* ln2_w    = (const float*)d_in[4];
  const float* ln2_b    = (const float*)d_in[5];
  const float* w_qkv    = (const float*)d_in[6];
  const float* edge_w   = (const float*)d_in[7];
  const float* edge_b   = (const float*)d_in[8];
  const float* out_w    = (const float*)d_in[9];
  const float* out_b    = (const float*)d_in[10];
  const float* ffn_w1   = (const float*)d_in[11];
  const float* ffn_b1   = (const float*)d_in[12];
  const float* ffn_w2   = (const float*)d_in[13];
  const float* ffn_b2   = (const float*)d_in[14];
  float* out = (float*)d_out;

  // workspace layout (floats) — compacted via buffer reuse, peak 54.5 MB
  float* ws = (float*)d_ws;
  float* qkv    = ws;                 // 3,145,728 f  (2048 x 1536)
  float* scores = ws + 3145728;       // 8,388,608 f  (32 x 512 x 512)
  float* x      = ws + 11534336;      // 1,048,576 f  (LN1 out; reused as attn)
  float* slots2 = ws + 12582912;      // 1,048,576 f  (end 13,631,488 f = 54.5 MB)
  float* attn   = x;                  // x dead after qkv GEMM
  float* y      = scores;             // scores dead after attn GEMM
  float* hbuf   = scores + 1048576;   // 4,194,304 f, after y, inside scores region

  // 1. x = LN1(slots)
  ln_kernel<<<2048, 256, 0, stream>>>(slots, ln1_w, ln1_b, x);
  // 2. qkv = x @ w_qkv   (2048 x 1536 x 512)
  gemm_nn<0,1><<<dim3(24,32,1), 256, 0, stream>>>(
      x, w_qkv, qkv, 2048, 1536, 512, 512, 1536, 1536,
      0,0,0,0,0,0, nullptr, nullptr);
  // 3. scores = edge bias
  edge_bias_kernel<<<8192, 256, 0, stream>>>(pairwise, edge_w, edge_b, scores);
  // 4. scores += 0.125 * Q@K^T  (batched over b,h)
  gemm_qk<<<dim3(8,8,32), 256, 0, stream>>>(qkv, scores);
  // 5. softmax rows
  softmax_kernel<<<16384, 256, 0, stream>>>(scores);
  // 6. attn = probs @ V   (batched; M=512,N=64,K=512)
  gemm_nn<0,8><<<dim3(1,8,32), 256, 0, stream>>>(
      scores, qkv + 1024, attn, 512, 64, 512, 512, 1536, 512,
      2097152, 262144, 786432, 64, 262144, 64, nullptr, nullptr);
  // 7. slots2 = slots + attn @ out_w + out_b
  gemm_nn<2,1><<<dim3(8,32,1), 256, 0, stream>>>(
      attn, out_w, slots2, 2048, 512, 512, 512, 512, 512,
      0,0,0,0,0,0, out_b, slots);
  // 8. y = LN2(slots2)   (y aliases dead scores)
  ln_kernel<<<2048, 256, 0, stream>>>(slots2, ln2_w, ln2_b, y);
  // 9. hbuf = gelu(y @ ffn_w1 + ffn_b1)   (2048 x 2048 x 512)
  gemm_nn<3,1><<<dim3(32,32,1), 256, 0, stream>>>(
      y, ffn_w1, hbuf, 2048, 2048, 512, 512, 2048, 2048,
      0,0,0,0,0,0, ffn_b1, nullptr);
  // 10. out = slots2 + hbuf @ ffn_w2 + ffn_b2   (2048 x 512 x 2048)
  gemm_nn<2,1><<<dim3(8,32,1), 256, 0, stream>>>(
      hbuf, ffn_w2, out, 2048, 512, 2048, 2048, 512, 512,
      0,0,0,0,0,0, ffn_b2, slots2);
}

// Round 3
// 908.916 us; speedup vs baseline: 1.2572x; 1.2572x over previous
//
#include <hip/hip_runtime.h>
#include <hip/hip_bf16.h>

typedef __attribute__((ext_vector_type(8))) short bf16x8;
typedef __attribute__((ext_vector_type(4))) float f32x4;

#define DEV __device__ __forceinline__

DEV float ldf(const float* p){ return *p; }
DEV float ldf(const unsigned short* p){ return __uint_as_float(((unsigned)*p) << 16); }
DEV void stout(float* p, float v){ *p = v; }
DEV void stout(unsigned short* p, float v){
  __hip_bfloat16 h = __float2bfloat16(v);
  *p = *reinterpret_cast<unsigned short*>(&h);
}

// ---------------- LayerNorm: one block per 512-elem row, bf16 out ----------
__global__ __launch_bounds__(256) void ln_kernel(const float* __restrict__ in,
    const float* __restrict__ w, const float* __restrict__ bb,
    unsigned short* __restrict__ out)
{
  const int row = blockIdx.x;
  const int tid = threadIdx.x;
  const long base = (long)row * 512;
  float v0 = in[base + tid];
  float v1 = in[base + 256 + tid];
  float s = v0 + v1, ss = v0*v0 + v1*v1;
  #pragma unroll
  for (int o = 32; o > 0; o >>= 1){ s += __shfl_down(s, o); ss += __shfl_down(ss, o); }
  __shared__ float rA[4], rB[4];
  const int wid = tid >> 6, lid = tid & 63;
  if (lid == 0){ rA[wid] = s; rB[wid] = ss; }
  __syncthreads();
  s  = rA[0] + rA[1] + rA[2] + rA[3];
  ss = rB[0] + rB[1] + rB[2] + rB[3];
  float mu  = s * (1.f/512.f);
  float var = ss * (1.f/512.f) - mu*mu;
  float r   = rsqrtf(var + 1e-5f);
  stout(&out[base + tid],       (v0 - mu) * r * w[tid]       + bb[tid]);
  stout(&out[base + 256 + tid], (v1 - mu) * r * w[256 + tid] + bb[256 + tid]);
}

// ---------------- tiled transpose + convert to bf16: out[n][k] = in[k][n] --
template<typename TIN>
__global__ __launch_bounds__(256) void transpose_conv(
    const TIN* __restrict__ in, unsigned short* __restrict__ out,
    int ldin, int ldout, long sIn, long sOut)
{
  __shared__ float t[32][33];
  in  += (long)blockIdx.z * sIn;
  out += (long)blockIdx.z * sOut;
  const int n0 = blockIdx.x*32, k0 = blockIdx.y*32;
  const int c = threadIdx.x & 31, r0 = threadIdx.x >> 5;
  #pragma unroll
  for (int i = 0; i < 4; i++){
    int r = r0 + i*8;
    t[r][c] = ldf(&in[(long)(k0 + r)*ldin + n0 + c]);
  }
  __syncthreads();
  #pragma unroll
  for (int i = 0; i < 4; i++){
    int r = r0 + i*8;
    stout(&out[(long)(n0 + r)*ldout + k0 + c], t[c][r]);
  }
}

// ---------------- MFMA bf16 GEMM: C = A @ B'^T (both operands row x K) -----
// A: M x K bf16 (lda), B: N x K bf16 (ldb)  [i.e. B' is the N-major operand]
// EPI: 0 = store acc ; 2 = +bias+res (fp32) ; 3 = gelu(acc+bias) ; 4 = C += 0.125*acc
template<int MT,int NT,int WGM,int WGN,int WR,int WC,int EPI,typename TOUT,int BDIV>
__global__ __launch_bounds__(256) void mfma_gemm(
    const unsigned short* __restrict__ A, const unsigned short* __restrict__ B,
    TOUT* __restrict__ C,
    int lda, int ldb, int ldc, int Kd,
    long sA, long sA2, long sB, long sB2, long sC, long sC2,
    const float* __restrict__ bias, const float* __restrict__ res)
{
  const int bz = blockIdx.z;
  A += (long)(bz / BDIV) * sA + (long)(bz % BDIV) * sA2;
  B += (long)(bz / BDIV) * sB + (long)(bz % BDIV) * sB2;
  C += (long)(bz / BDIV) * sC + (long)(bz % BDIV) * sC2;
  if (res) res += (long)(bz / BDIV) * sC + (long)(bz % BDIV) * sC2;
  __shared__ unsigned short As[MT][40];   // +8 pad: 2-way LDS banks (free)
  __shared__ unsigned short Bs[NT][40];
  const int tid  = threadIdx.x;
  const int lane = tid & 63, wv = tid >> 6;
  const int quad = lane >> 4, l16 = lane & 15;
  const int wm = (wv % WGM) * WR * 16;
  const int wn = (wv / WGM) * WC * 16;
  const int m0 = blockIdx.y * MT, n0 = blockIdx.x * NT;
  f32x4 acc[WR][WC] = {};
  for (int k0 = 0; k0 < Kd; k0 += 32){
    #pragma unroll
    for (int it = 0; it < MT*32/(256*8); ++it){
      int idx = (it*256 + tid) * 8;
      int r = idx >> 5, c = idx & 31;
      *(uint4*)&As[r][c] = *(const uint4*)&A[(long)(m0 + r)*lda + k0 + c];
    }
    #pragma unroll
    for (int it = 0; it < NT*32/(256*8); ++it){
      int idx = (it*256 + tid) * 8;
      int r = idx >> 5, c = idx & 31;
      *(uint4*)&Bs[r][c] = *(const uint4*)&B[(long)(n0 + r)*ldb + k0 + c];
    }
    __syncthreads();
    bf16x8 af[WR], bfr[WC];
    #pragma unroll
    for (int i = 0; i < WR; i++) af[i]  = *(const bf16x8*)&As[wm + i*16 + l16][quad*8];
    #pragma unroll
    for (int j = 0; j < WC; j++) bfr[j] = *(const bf16x8*)&Bs[wn + j*16 + l16][quad*8];
    #pragma unroll
    for (int i = 0; i < WR; i++)
      #pragma unroll
      for (int j = 0; j < WC; j++)
        acc[i][j] = __builtin_amdgcn_mfma_f32_16x16x32_bf16(af[i], bfr[j], acc[i][j], 0, 0, 0);
    __syncthreads();
  }
  // epilogue: C/D layout col=lane&15, row=quad*4+reg (verified mapping)
  #pragma unroll
  for (int i = 0; i < WR; i++){
    #pragma unroll
    for (int j = 0; j < WC; j++){
      #pragma unroll
      for (int r = 0; r < 4; r++){
        int m = m0 + wm + i*16 + quad*4 + r;
        int n = n0 + wn + j*16 + l16;
        float v = acc[i][j][r];
        long idx = (long)m * ldc + n;
        if (EPI == 0){ stout(&C[idx], v); }
        else if (EPI == 2){ stout(&C[idx], v + bias[n] + res[idx]); }
        else if (EPI == 3){
          v += bias[n];
          v = 0.5f * v * (1.f + erff(v * 0.70710678118f));
          stout(&C[idx], v);
        }
        else if (EPI == 4){ ((float*)C)[idx] += 0.125f * v; }
      }
    }
  }
}

// ---------------- softmax over rows of 512: fp32 in -> bf16 out ------------
__global__ __launch_bounds__(256) void softmax_kernel(
    const float* __restrict__ sc, unsigned short* __restrict__ pr)
{
  const long base = (long)blockIdx.x * 512;
  const int tid = threadIdx.x;
  float a = sc[base + tid], b = sc[base + 256 + tid];
  float m = fmaxf(a, b);
  #pragma unroll
  for (int o = 32; o > 0; o >>= 1) m = fmaxf(m, __shfl_xor(m, o));
  __shared__ float rA[4], rB[4];
  const int wid = tid >> 6, lid = tid & 63;
  if (lid == 0) rA[wid] = m;
  __syncthreads();
  m = fmaxf(fmaxf(rA[0], rA[1]), fmaxf(rA[2], rA[3]));
  float ea = __expf(a - m), eb = __expf(b - m);
  float s = ea + eb;
  #pragma unroll
  for (int o = 32; o > 0; o >>= 1) s += __shfl_xor(s, o);
  if (lid == 0) rB[wid] = s;
  __syncthreads();
  s = rB[0] + rB[1] + rB[2] + rB[3];
  float inv = 1.f / s;
  stout(&pr[base + tid],       ea * inv);
  stout(&pr[base + 256 + tid], eb * inv);
}

// ---------------- edge bias (fp32): scores[b,h,q,k] = pw[b,q,k,:]·ew[:,h]+eb[h]
__global__ __launch_bounds__(256) void edge_bias_kernel(
    const float* __restrict__ pw,
    const float* __restrict__ edge_w,
    const float* __restrict__ edge_b,
    float* __restrict__ scores)
{
  const int tid  = threadIdx.x;
  const int lane = tid & 63;
  const int wid  = tid >> 6;
  const int sub  = lane & 15;
  const int quad = lane >> 4;
  float ew[8][8];
  #pragma unroll
  for (int j = 0; j < 8; j++)
    #pragma unroll
    for (int h = 0; h < 8; h++)
      ew[j][h] = edge_w[(sub*8 + j)*8 + h];
  const int b3 = (sub >> 3) & 1, b2_ = (sub >> 2) & 1, b1 = (sub >> 1) & 1;
  const int myh = b3*4 + b2_*2 + b1;
  const float ebh = edge_b[myh];
  const long total = 1048576;  // 4*512*512 pairs
  for (long base = (long)blockIdx.x * 16; base < total; base += (long)gridDim.x * 16){
    long pair = base + wid*4 + quad;
    const float* src = pw + pair * 128 + sub * 8;
    float4 r0 = *reinterpret_cast<const float4*>(src);
    float4 r1 = *reinterpret_cast<const float4*>(src + 4);
    float x[8] = {r0.x, r0.y, r0.z, r0.w, r1.x, r1.y, r1.z, r1.w};
    float acc[8] = {0,0,0,0,0,0,0,0};
    #pragma unroll
    for (int j = 0; j < 8; j++)
      #pragma unroll
      for (int h = 0; h < 8; h++)
        acc[h] += x[j] * ew[j][h];
    float t[4];
    #pragma unroll
    for (int i = 0; i < 4; i++){
      float send = b3 ? acc[i] : acc[i+4];
      float keep = b3 ? acc[i+4] : acc[i];
      t[i] = keep + __shfl_xor(send, 8);
    }
    float u[2];
    #pragma unroll
    for (int i = 0; i < 2; i++){
      float send = b2_ ? t[i] : t[i+2];
      float keep = b2_ ? t[i+2] : t[i];
      u[i] = keep + __shfl_xor(send, 4);
    }
    float send = b1 ? u[0] : u[1];
    float keep = b1 ? u[1] : u[0];
    float val = keep + __shfl_xor(send, 2);
    val += __shfl_xor(val, 1);
    if ((sub & 1) == 0){
      long b  = pair >> 18;
      long qk = pair & 262143;
      scores[(b*8 + myh) * 262144 + qk] = val + ebh;
    }
  }
}

// ---------------------------------------------------------------------------
extern "C" void kernel_launch(void* const* d_in, const int* in_sizes, int n_in,
                              void* d_out, int out_size, void* d_ws, size_t ws_size,
                              hipStream_t stream)
{
  const float* slots    = (const float*)d_in[0];
  const float* pairwise = (const float*)d_in[1];
  const float* ln1_w    = (const float*)d_in[2];
  const float* ln1_b    = (const float*)d_in[3];
  const float* ln2_w    = (const float*)d_in[4];
  const float* ln2_b    = (const float*)d_in[5];
  const float* w_qkv    = (const float*)d_in[6];
  const float* edge_w   = (const float*)d_in[7];
  const float* edge_b   = (const float*)d_in[8];
  const float* out_w    = (const float*)d_in[9];
  const float* out_b    = (const float*)d_in[10];
  const float* ffn_w1   = (const float*)d_in[11];
  const float* ffn_b1   = (const float*)d_in[12];
  const float* ffn_w2   = (const float*)d_in[13];
  const float* ffn_b2   = (const float*)d_in[14];
  float* out = (float*)d_out;

  // ---- workspace layout ----
  float* ws      = (float*)d_ws;
  float* scores  = ws;                       // 8,388,608 f (32x512x512)
  float* slots2  = ws + 8388608;             // 1,048,576 f
  unsigned short* ub = (unsigned short*)(ws + 9437184);
  unsigned short* x_b    = ub;               // 2048x512
  unsigned short* qkv_b  = ub + 1048576;     // 2048x1536
  unsigned short* probs  = ub + 4194304;     // 32x512x512
  unsigned short* vt_b   = ub + 12582912;    // 32x64x512
  unsigned short* attn_b = ub + 13631488;    // 2048x512
  unsigned short* y_b    = ub + 14680064;    // 2048x512
  unsigned short* h_b    = ub + 15728640;    // 2048x2048
  unsigned short* wqkvT  = ub + 19922944;    // 1536x512
  unsigned short* outwT  = ub + 20709376;    // 512x512
  unsigned short* w1T    = ub + 20971520;    // 2048x512
  unsigned short* w2T    = ub + 22020096;    // 512x2048
  // total ≈ 84 MB

  // ---- weight transposes (fp32 -> bf16, N x K layout) ----
  transpose_conv<float><<<dim3(48,16,1), 256, 0, stream>>>(w_qkv,  wqkvT, 1536, 512, 0, 0);
  transpose_conv<float><<<dim3(16,16,1), 256, 0, stream>>>(out_w,  outwT, 512,  512, 0, 0);
  transpose_conv<float><<<dim3(64,16,1), 256, 0, stream>>>(ffn_w1, w1T,   2048, 512, 0, 0);
  transpose_conv<float><<<dim3(16,64,1), 256, 0, stream>>>(ffn_w2, w2T,   512, 2048, 0, 0);

  // 1. x_b = LN1(slots), bf16
  ln_kernel<<<2048, 256, 0, stream>>>(slots, ln1_w, ln1_b, x_b);
  // 2. qkv_b = x_b @ w_qkv  (2048 x 1536 x 512), bf16 out
  mfma_gemm<128,128,2,2,4,4,0,unsigned short,1><<<dim3(12,16,1), 256, 0, stream>>>(
      x_b, wqkvT, qkv_b, 512, 512, 1536, 512,
      0,0,0,0,0,0, nullptr, nullptr);
  // 3. scores = edge bias (fp32)
  edge_bias_kernel<<<8192, 256, 0, stream>>>(pairwise, edge_w, edge_b, scores);
  // 4. scores += 0.125 * Q @ K^T  (batched over b,h; Kd=64)
  mfma_gemm<128,128,2,2,4,4,4,float,8><<<dim3(4,4,32), 256, 0, stream>>>(
      qkv_b, qkv_b + 512, scores, 1536, 1536, 512, 64,
      786432, 64, 786432, 64, 2097152, 262144, nullptr, nullptr);
  // 5. probs = softmax(scores), bf16
  softmax_kernel<<<16384, 256, 0, stream>>>(scores, probs);
  // 6. vt_b[bh][d][q] = V  (batched bf16 transpose of the V slice)
  transpose_conv<unsigned short><<<dim3(16,16,4), 256, 0, stream>>>(
      qkv_b + 1024, vt_b, 1536, 512, 786432, 262144);
  // 7. attn_b = probs @ V  (M=512,N=64,K=512 per bh), bf16 out in (b,q,h,d)
  mfma_gemm<128,64,4,1,2,4,0,unsigned short,8><<<dim3(1,4,32), 256, 0, stream>>>(
      probs, vt_b, attn_b, 512, 512, 512, 512,
      2097152, 262144, 262144, 32768, 262144, 64, nullptr, nullptr);
  // 8. slots2 = slots + attn_b @ out_w + out_b  (fp32)
  mfma_gemm<64,128,1,4,4,2,2,float,1><<<dim3(4,32,1), 256, 0, stream>>>(
      attn_b, outwT, slots2, 512, 512, 512, 512,
      0,0,0,0,0,0, out_b, slots);
  // 9. y_b = LN2(slots2), bf16
  ln_kernel<<<2048, 256, 0, stream>>>(slots2, ln2_w, ln2_b, y_b);
  // 10. h_b = gelu(y_b @ ffn_w1 + ffn_b1)  (2048 x 2048 x 512), bf16
  mfma_gemm<128,128,2,2,4,4,3,unsigned short,1><<<dim3(16,16,1), 256, 0, stream>>>(
      y_b, w1T, h_b, 512, 512, 2048, 512,
      0,0,0,0,0,0, ffn_b1, nullptr);
  // 11. out = slots2 + h_b @ ffn_w2 + ffn_b2  (2048 x 512 x 2048), fp32
  mfma_gemm<64,128,1,4,4,2,2,float,1><<<dim3(4,32,1), 256, 0, stream>>>(
      h_b, w2T, out, 2048, 2048, 512, 2048,
      0,0,0,0,0,0, ffn_b2, slots2);
}